// Round 6
// baseline (425.413 us; speedup 1.0000x reference)
//
#include <hip/hip_runtime.h>
#include <cstdint>
#include <cstddef>

// ---------------------------------------------------------------------------
// StationGNN: 3x GraphSAGE(mean) + MLP head.
// R1: fused head MLP. R2: parallel scan. R3: split-bf16 MFMA GEMMs.
// R4: hi-only bf16 gather in aggregation.
// R5: bucketed two-pass CSR fill (was 50us: random 4B scatters -> 51MB of
//     line-allocate writes). Buckets=128-node ranges; bases free from
//     row_ptr; pass D uses LDS cursors, zero global atomics.
// ---------------------------------------------------------------------------

typedef __attribute__((ext_vector_type(8))) short short8;
typedef __attribute__((ext_vector_type(8))) unsigned short ushort8;
typedef __attribute__((ext_vector_type(4))) float floatx4;

__device__ __forceinline__ float bf2f(unsigned short h) {
    return __uint_as_float(((unsigned int)h) << 16);
}
__device__ __forceinline__ void split2(float x, unsigned short& hi, unsigned short& lo) {
    unsigned int u = __float_as_uint(x);
    hi = (unsigned short)(u >> 16);
    float r = x - __uint_as_float(u & 0xFFFF0000u);
    lo = (unsigned short)(__float_as_uint(r) >> 16);
}

// ------------------------------ CSR build ----------------------------------

__global__ void deg_count_kernel(const int* __restrict__ dst, int E,
                                 int* __restrict__ deg) {
    int e = blockIdx.x * 256 + threadIdx.x;
    if (e < E) atomicAdd(&deg[dst[e]], 1);
}

__global__ __launch_bounds__(1024) void scan_partial_kernel(const int* __restrict__ deg,
                                                            int N, int* __restrict__ excl,
                                                            int* __restrict__ blockSums) {
    __shared__ int sdata[1024];
    int tid = threadIdx.x;
    int idx = blockIdx.x * 1024 + tid;
    int v = (idx < N) ? deg[idx] : 0;
    sdata[tid] = v;
    __syncthreads();
    for (int off = 1; off < 1024; off <<= 1) {
        int t = (tid >= off) ? sdata[tid - off] : 0;
        __syncthreads();
        sdata[tid] += t;
        __syncthreads();
    }
    if (idx < N) excl[idx] = sdata[tid] - v;
    if (tid == 1023) blockSums[blockIdx.x] = sdata[1023];
}

__global__ void scan_sums_kernel(int* __restrict__ blockSums, int nb,
                                 int* __restrict__ row_ptr, int N) {
    if (threadIdx.x == 0 && blockIdx.x == 0) {
        int run = 0;
        for (int i = 0; i < nb; ++i) { int t = blockSums[i]; blockSums[i] = run; run += t; }
        row_ptr[N] = run;
    }
}

__global__ void scan_add_kernel(int* __restrict__ row_ptr,
                                const int* __restrict__ blockSums, int N) {
    int idx = blockIdx.x * 256 + threadIdx.x;
    if (idx < N) row_ptr[idx] += blockSums[idx >> 10];
}

// bucket cursors (one per 64B line): bcursor[b*16] = row_ptr[b*128]
__global__ void bcursor_init_kernel(const int* __restrict__ row_ptr,
                                    int* __restrict__ bcursor, int NB) {
    int b = blockIdx.x * 256 + threadIdx.x;
    if (b < NB) bcursor[b * 16] = row_ptr[b * 128];
}

// Pass C: scatter packed edges into bucket-contiguous regions of ebuf
__global__ void scatter_kernel(const int* __restrict__ src, const int* __restrict__ dst,
                               int E, int* __restrict__ bcursor,
                               unsigned int* __restrict__ ebuf) {
    int e = blockIdx.x * 256 + threadIdx.x;
    if (e < E) {
        int d = dst[e];
        int s = src[e];
        int b = d >> 7;
        int p = atomicAdd(&bcursor[b * 16], 1);
        ebuf[p] = (unsigned int)s | ((unsigned int)d << 16);
    }
}

// Pass D: one block per bucket; LDS per-node cursors; col writes land in the
// bucket's contiguous col window (full line utilization).
__global__ __launch_bounds__(256) void bucket_fill_kernel(const int* __restrict__ row_ptr,
                                                          const unsigned int* __restrict__ ebuf,
                                                          int* __restrict__ col, int N) {
    __shared__ int cur[128];
    int b = blockIdx.x;
    int nbase = b * 128;
    int i = threadIdx.x;
    if (i < 128 && nbase + i < N) cur[i] = row_ptr[nbase + i];
    __syncthreads();
    int nend = nbase + 128; if (nend > N) nend = N;
    int beg = row_ptr[nbase];
    int end = row_ptr[nend];
    for (int e = beg + threadIdx.x; e < end; e += 256) {
        unsigned int v = ebuf[e];
        int s = (int)(v & 0xFFFFu);
        int d = (int)(v >> 16);
        int p = atomicAdd(&cur[d - nbase], 1);
        col[p] = s;
    }
}

// --------------------------- fp32 -> (hi,lo) -------------------------------

__global__ void convert_x_kernel(const float* __restrict__ x,
                                 unsigned short* __restrict__ xH,
                                 unsigned short* __restrict__ xL, int total4) {
    int i = blockIdx.x * 256 + threadIdx.x;
    if (i >= total4) return;
    float4 v = ((const float4*)x)[i];
    unsigned short h0, h1, h2, h3, l0, l1, l2, l3;
    split2(v.x, h0, l0); split2(v.y, h1, l1); split2(v.z, h2, l2); split2(v.w, h3, l3);
    ((ushort4*)xH)[i] = make_ushort4(h0, h1, h2, h3);
    ((ushort4*)xL)[i] = make_ushort4(l0, l1, l2, l3);
}

__global__ void convert_w_kernel(const float* __restrict__ w0, const float* __restrict__ w1,
                                 const float* __restrict__ w2, const float* __restrict__ w3,
                                 const float* __restrict__ w4, const float* __restrict__ w5,
                                 unsigned short* __restrict__ WH,
                                 unsigned short* __restrict__ WL) {
    int m = blockIdx.y;
    const float* src = (m == 0) ? w0 : (m == 1) ? w1 : (m == 2) ? w2
                       : (m == 3) ? w3 : (m == 4) ? w4 : w5;
    int i = blockIdx.x * 256 + threadIdx.x;
    if (i >= 4096) return;
    float4 v = ((const float4*)src)[i];
    unsigned short h0, h1, h2, h3, l0, l1, l2, l3;
    split2(v.x, h0, l0); split2(v.y, h1, l1); split2(v.z, h2, l2); split2(v.w, h3, l3);
    ((ushort4*)(WH + (size_t)m * 16384))[i] = make_ushort4(h0, h1, h2, h3);
    ((ushort4*)(WL + (size_t)m * 16384))[i] = make_ushort4(l0, l1, l2, l3);
}

// ------------------------------ aggregation --------------------------------

__global__ __launch_bounds__(256) void agg_mean_kernel(
    const unsigned short* __restrict__ inH,
    const int* __restrict__ row_ptr, const int* __restrict__ col,
    unsigned short* __restrict__ mH, unsigned short* __restrict__ mL, int N) {
    int wave = threadIdx.x >> 6;
    int lane = threadIdx.x & 63;
    int n = blockIdx.x * 4 + wave;
    if (n >= N) return;
    int beg = row_ptr[n];
    int end = row_ptr[n + 1];
    float ax = 0.f, ay = 0.f, bx = 0.f, by = 0.f;
    float cx = 0.f, cy = 0.f, dx = 0.f, dy = 0.f;
    int i = beg;
    for (; i + 3 < end; i += 4) {
        int s0 = col[i], s1 = col[i + 1], s2 = col[i + 2], s3 = col[i + 3];
        ushort2 h0 = ((const ushort2*)(inH + (size_t)s0 * 128))[lane];
        ushort2 h1 = ((const ushort2*)(inH + (size_t)s1 * 128))[lane];
        ushort2 h2 = ((const ushort2*)(inH + (size_t)s2 * 128))[lane];
        ushort2 h3 = ((const ushort2*)(inH + (size_t)s3 * 128))[lane];
        ax += bf2f(h0.x); ay += bf2f(h0.y);
        bx += bf2f(h1.x); by += bf2f(h1.y);
        cx += bf2f(h2.x); cy += bf2f(h2.y);
        dx += bf2f(h3.x); dy += bf2f(h3.y);
    }
    for (; i < end; ++i) {
        int s0 = col[i];
        ushort2 h0 = ((const ushort2*)(inH + (size_t)s0 * 128))[lane];
        ax += bf2f(h0.x); ay += bf2f(h0.y);
    }
    int d = end - beg;
    float inv = 1.0f / (float)(d > 0 ? d : 1);
    float vx = (ax + bx + cx + dx) * inv, vy = (ay + by + cy + dy) * inv;
    unsigned short hx, lx, hy, ly;
    split2(vx, hx, lx); split2(vy, hy, ly);
    ((ushort2*)(mH + (size_t)n * 128))[lane] = make_ushort2(hx, hy);
    ((ushort2*)(mL + (size_t)n * 128))[lane] = make_ushort2(lx, ly);
}

// ------------------------- split-bf16 MFMA GEMM ----------------------------

__global__ __launch_bounds__(256, 2) void sage_gemm_mfma(
    const unsigned short* __restrict__ a0H, const unsigned short* __restrict__ a0L,
    const unsigned short* __restrict__ a1H, const unsigned short* __restrict__ a1L,
    const unsigned short* __restrict__ w0H, const unsigned short* __restrict__ w0L,
    const unsigned short* __restrict__ w1H, const unsigned short* __restrict__ w1L,
    const float* __restrict__ bias,
    unsigned short* __restrict__ outH, unsigned short* __restrict__ outL, int N) {
    __shared__ unsigned short Ah[128][40];
    __shared__ unsigned short Al[128][40];
    __shared__ unsigned short Wh[128][40];
    __shared__ unsigned short Wl[128][40];
    int tid = threadIdx.x;
    int n0 = blockIdx.x * 128;
    int wv = tid >> 6, lane = tid & 63;
    int wm = wv & 1, wn = wv >> 1;
    int r16 = lane & 15, q = lane >> 4, q8 = q * 8;

    floatx4 acc[4][4];
#pragma unroll
    for (int mi = 0; mi < 4; ++mi)
#pragma unroll
        for (int ni = 0; ni < 4; ++ni) {
            floatx4 z = {0.f, 0.f, 0.f, 0.f};
            acc[mi][ni] = z;
        }

    int tc = (tid & 3) * 8;
    int tr = tid >> 2;

    for (int part = 0; part < 2; ++part) {
        const unsigned short* AH = part ? a1H : a0H;
        const unsigned short* AL = part ? a1L : a0L;
        const unsigned short* WHp = part ? w1H : w0H;
        const unsigned short* WLp = part ? w1L : w0L;
        for (int kk = 0; kk < 128; kk += 32) {
            __syncthreads();
#pragma unroll
            for (int rr = 0; rr < 2; ++rr) {
                int row = tr + 64 * rr;
                int n = n0 + row;
                ushort8 vh = {0, 0, 0, 0, 0, 0, 0, 0};
                ushort8 vl = {0, 0, 0, 0, 0, 0, 0, 0};
                if (n < N) {
                    vh = *(const ushort8*)&AH[(size_t)n * 128 + kk + tc];
                    vl = *(const ushort8*)&AL[(size_t)n * 128 + kk + tc];
                }
                *(ushort8*)&Ah[row][tc] = vh;
                *(ushort8*)&Al[row][tc] = vl;
                *(ushort8*)&Wh[row][tc] = *(const ushort8*)&WHp[(size_t)row * 128 + kk + tc];
                *(ushort8*)&Wl[row][tc] = *(const ushort8*)&WLp[(size_t)row * 128 + kk + tc];
            }
            __syncthreads();
            short8 ah[4], al[4];
#pragma unroll
            for (int mi = 0; mi < 4; ++mi) {
                int row = 64 * wm + 16 * mi + r16;
                ah[mi] = *(const short8*)&Ah[row][q8];
                al[mi] = *(const short8*)&Al[row][q8];
            }
#pragma unroll
            for (int ni = 0; ni < 4; ++ni) {
                int row = 64 * wn + 16 * ni + r16;
                short8 bh = *(const short8*)&Wh[row][q8];
                short8 bl = *(const short8*)&Wl[row][q8];
#pragma unroll
                for (int mi = 0; mi < 4; ++mi) {
                    acc[mi][ni] = __builtin_amdgcn_mfma_f32_16x16x32_bf16(ah[mi], bh, acc[mi][ni], 0, 0, 0);
                    acc[mi][ni] = __builtin_amdgcn_mfma_f32_16x16x32_bf16(al[mi], bh, acc[mi][ni], 0, 0, 0);
                    acc[mi][ni] = __builtin_amdgcn_mfma_f32_16x16x32_bf16(ah[mi], bl, acc[mi][ni], 0, 0, 0);
                }
            }
        }
    }
#pragma unroll
    for (int ni = 0; ni < 4; ++ni) {
        int j = 64 * wn + 16 * ni + r16;
        float b = bias[j];
#pragma unroll
        for (int mi = 0; mi < 4; ++mi) {
            floatx4 v = acc[mi][ni];
#pragma unroll
            for (int p = 0; p < 4; ++p) {
                int node = n0 + 64 * wm + 16 * mi + 4 * q + p;
                if (node < N) {
                    float val = fmaxf(v[p] + b, 0.f);
                    unsigned short hi, lo;
                    split2(val, hi, lo);
                    outH[(size_t)node * 128 + j] = hi;
                    outL[(size_t)node * 128 + j] = lo;
                }
            }
        }
    }
}

// ------------------------------ fused head ---------------------------------

__global__ __launch_bounds__(256) void head_fused_kernel(
    const unsigned short* __restrict__ hH, const unsigned short* __restrict__ hL,
    const float* __restrict__ Wh1, const float* __restrict__ bh1,
    const float* __restrict__ Wh2, const float* __restrict__ bh2,
    float* __restrict__ out, int N) {
    __shared__ float As[64][33];
    __shared__ float Bs[32][65];
    __shared__ float Hs[64][65];
    int tid = threadIdx.x;
    int n0 = blockIdx.x * 64;
    int ti = tid & 15;
    int tj = tid >> 4;

    float acc[4][4];
#pragma unroll
    for (int r = 0; r < 4; ++r)
#pragma unroll
        for (int c = 0; c < 4; ++c) acc[r][c] = 0.f;

    for (int kk = 0; kk < 128; kk += 32) {
        int ks = tid & 31, i0 = tid >> 5;
#pragma unroll
        for (int r = 0; r < 8; ++r) {
            int i = i0 + 8 * r;
            int n = n0 + i;
            As[i][ks] = (n < N)
                ? (bf2f(hH[(size_t)n * 128 + kk + ks]) + bf2f(hL[(size_t)n * 128 + kk + ks]))
                : 0.f;
        }
        int jj0 = tid >> 5;
#pragma unroll
        for (int r = 0; r < 8; ++r) {
            int j = jj0 + 8 * r;
            Bs[ks][j] = Wh1[(size_t)j * 128 + kk + ks];
        }
        __syncthreads();
#pragma unroll 4
        for (int k = 0; k < 32; ++k) {
            float4 b = *(const float4*)&Bs[k][4 * tj];
#pragma unroll
            for (int r = 0; r < 4; ++r) {
                float a = As[4 * ti + r][k];
                acc[r][0] += a * b.x; acc[r][1] += a * b.y;
                acc[r][2] += a * b.z; acc[r][3] += a * b.w;
            }
        }
        __syncthreads();
    }
    float4 bv = *(const float4*)&bh1[4 * tj];
#pragma unroll
    for (int r = 0; r < 4; ++r) {
        int i = 4 * ti + r;
        Hs[i][4 * tj + 0] = fmaxf(acc[r][0] + bv.x, 0.f);
        Hs[i][4 * tj + 1] = fmaxf(acc[r][1] + bv.y, 0.f);
        Hs[i][4 * tj + 2] = fmaxf(acc[r][2] + bv.z, 0.f);
        Hs[i][4 * tj + 3] = fmaxf(acc[r][3] + bv.w, 0.f);
    }
    __syncthreads();
    int ni = tid >> 2;
    int c = tid & 3;
    const float* w = Wh2 + (size_t)c * 64;
    float s = bh2[c];
#pragma unroll 8
    for (int k = 0; k < 64; ++k) s += Hs[ni][k] * w[k];
    int n = n0 + ni;
    if (n < N) out[(size_t)n * 4 + c] = s;
}

// ------------------------------- launcher ----------------------------------

extern "C" void kernel_launch(void* const* d_in, const int* in_sizes, int n_in,
                              void* d_out, int out_size, void* d_ws, size_t ws_size,
                              hipStream_t stream) {
    const float* x   = (const float*)d_in[0];
    const int*   ei  = (const int*)d_in[1];
    const float* Wl0 = (const float*)d_in[2];
    const float* bl0 = (const float*)d_in[3];
    const float* Wr0 = (const float*)d_in[4];
    const float* Wl1 = (const float*)d_in[5];
    const float* bl1 = (const float*)d_in[6];
    const float* Wr1 = (const float*)d_in[7];
    const float* Wl2 = (const float*)d_in[8];
    const float* bl2 = (const float*)d_in[9];
    const float* Wr2 = (const float*)d_in[10];
    const float* Wh1 = (const float*)d_in[11];
    const float* bh1 = (const float*)d_in[12];
    const float* Wh2 = (const float*)d_in[13];
    const float* bh2 = (const float*)d_in[14];
    float* out = (float*)d_out;

    const int N = in_sizes[0] / 128;
    const int E = in_sizes[1] / 2;
    const int* src = ei;
    const int* dst = ei + E;
    const int NB = (N + 127) / 128;        // buckets of 128 nodes

    int* deg       = (int*)d_ws;            // N
    int* row_ptr   = deg + N;               // N+1
    int* blockSums = row_ptr + N + 1;       // <= 64
    int* bcursor   = blockSums + 64;        // NB*16 (line-padded)
    unsigned int* ebuf = (unsigned int*)(bcursor + (size_t)NB * 16);  // E
    int* col       = (int*)(ebuf + E);      // E
    size_t ioff = (((size_t)(2 * N + 1 + 64 + (size_t)NB * 16 + 2 * (size_t)E)) * sizeof(int) + 255) & ~(size_t)255;
    unsigned short* u0H = (unsigned short*)((char*)d_ws + ioff);  // x pairs / hB pairs
    unsigned short* u0L = u0H + (size_t)N * 128;
    unsigned short* mH  = u0L + (size_t)N * 128;                  // mean pairs
    unsigned short* mL  = mH + (size_t)N * 128;
    unsigned short* aH  = mL + (size_t)N * 128;                   // hA pairs
    unsigned short* aL  = aH + (size_t)N * 128;
    unsigned short* WH  = aL + (size_t)N * 128;                   // 6 x 16384
    unsigned short* WL  = WH + 6 * 16384;

    const int eb = (E + 255) / 256;
    const int nb4 = (N + 3) / 4;
    const int gb64 = (N + 63) / 64;
    const int gb128 = (N + 127) / 128;
    const int sb = (N + 1023) / 1024;

    // CSR build
    hipMemsetAsync(deg, 0, (size_t)N * sizeof(int), stream);
    deg_count_kernel<<<eb, 256, 0, stream>>>(dst, E, deg);
    scan_partial_kernel<<<sb, 1024, 0, stream>>>(deg, N, row_ptr, blockSums);
    scan_sums_kernel<<<1, 64, 0, stream>>>(blockSums, sb, row_ptr, N);
    scan_add_kernel<<<(N + 255) / 256, 256, 0, stream>>>(row_ptr, blockSums, N);
    bcursor_init_kernel<<<(NB + 255) / 256, 256, 0, stream>>>(row_ptr, bcursor, NB);
    scatter_kernel<<<eb, 256, 0, stream>>>(src, dst, E, bcursor, ebuf);
    bucket_fill_kernel<<<NB, 256, 0, stream>>>(row_ptr, ebuf, col, N);

    // convert inputs to (hi,lo) pairs
    convert_x_kernel<<<(N * 32 + 255) / 256, 256, 0, stream>>>(x, u0H, u0L, N * 32);
    dim3 wgrid(16, 6);
    convert_w_kernel<<<wgrid, 256, 0, stream>>>(Wl0, Wr0, Wl1, Wr1, Wl2, Wr2, WH, WL);

    // layer 0: A0=mean(x), A1=x
    agg_mean_kernel<<<nb4, 256, 0, stream>>>(u0H, row_ptr, col, mH, mL, N);
    sage_gemm_mfma<<<gb128, 256, 0, stream>>>(mH, mL, u0H, u0L,
                                              WH + 0 * 16384, WL + 0 * 16384,
                                              WH + 1 * 16384, WL + 1 * 16384,
                                              bl0, aH, aL, N);
    // layer 1
    agg_mean_kernel<<<nb4, 256, 0, stream>>>(aH, row_ptr, col, mH, mL, N);
    sage_gemm_mfma<<<gb128, 256, 0, stream>>>(mH, mL, aH, aL,
                                              WH + 2 * 16384, WL + 2 * 16384,
                                              WH + 3 * 16384, WL + 3 * 16384,
                                              bl1, u0H, u0L, N);
    // layer 2
    agg_mean_kernel<<<nb4, 256, 0, stream>>>(u0H, row_ptr, col, mH, mL, N);
    sage_gemm_mfma<<<gb128, 256, 0, stream>>>(mH, mL, u0H, u0L,
                                              WH + 4 * 16384, WL + 4 * 16384,
                                              WH + 5 * 16384, WL + 5 * 16384,
                                              bl2, aH, aL, N);

    // fused head MLP
    head_fused_kernel<<<gb64, 256, 0, stream>>>(aH, aL, Wh1, bh1, Wh2, bh2, out, N);
}

// Round 7
// 399.761 us; speedup vs baseline: 1.0642x; 1.0642x over previous
//
#include <hip/hip_runtime.h>
#include <cstdint>
#include <cstddef>

// ---------------------------------------------------------------------------
// StationGNN: 3x GraphSAGE(mean) + MLP head.
// R1: fused head. R2: parallel scan. R3: split-bf16 MFMA GEMMs.
// R4: hi-only bf16 gather. R5: bucketed fill (FAILED: shared frontier lines
//     across XCDs -> 40MB writes).
// R6: counting-sort binning. Each block reserves PRIVATE contiguous runs per
//     bucket (one global atomicAdd per block x bucket), so scatter frontier
//     lines are CU-exclusive and merge in L2. CSR row_ptr derived per-bucket
//     from LDS histogram+scan (deg_count + 3 scan kernels eliminated).
// ---------------------------------------------------------------------------

typedef __attribute__((ext_vector_type(8))) short short8;
typedef __attribute__((ext_vector_type(8))) unsigned short ushort8;
typedef __attribute__((ext_vector_type(4))) float floatx4;

#define BSHIFT 8                 // 256 nodes per bucket
#define MAXB 512                 // supports N <= 131072

__device__ __forceinline__ float bf2f(unsigned short h) {
    return __uint_as_float(((unsigned int)h) << 16);
}
__device__ __forceinline__ void split2(float x, unsigned short& hi, unsigned short& lo) {
    unsigned int u = __float_as_uint(x);
    hi = (unsigned short)(u >> 16);
    float r = x - __uint_as_float(u & 0xFFFF0000u);
    lo = (unsigned short)(__float_as_uint(r) >> 16);
}

// ------------------------------ CSR build ----------------------------------

// coarse histogram of dst buckets
__global__ __launch_bounds__(256) void hist_kernel(const int* __restrict__ dst, int E,
                                                   int* __restrict__ bh, int NBUCK) {
    __shared__ int lh[MAXB];
    for (int i = threadIdx.x; i < NBUCK; i += 256) lh[i] = 0;
    __syncthreads();
    for (int e = blockIdx.x * 256 + threadIdx.x; e < E; e += gridDim.x * 256)
        atomicAdd(&lh[dst[e] >> BSHIFT], 1);
    __syncthreads();
    for (int i = threadIdx.x; i < NBUCK; i += 256)
        if (lh[i]) atomicAdd(&bh[i], lh[i]);
}

// single-block scan of NBUCK bucket counts -> bucket_base / bucket_cursor
__global__ __launch_bounds__(256) void bucket_scan_kernel(const int* __restrict__ bh,
                                                          int* __restrict__ bucket_base,
                                                          int* __restrict__ bucket_cursor,
                                                          int* __restrict__ row_ptr,
                                                          int NBUCK, int N, int E) {
    if (threadIdx.x == 0) {
        int run = 0;
        for (int i = 0; i < NBUCK; ++i) {
            bucket_base[i] = run;
            bucket_cursor[i] = run;
            run += bh[i];
        }
        bucket_base[NBUCK] = run;
        row_ptr[N] = E;
    }
}

// binsort: each block owns a contiguous edge chunk; reserves private runs
// per bucket; scatters packed (s|d<<16) into its exclusive runs.
__global__ __launch_bounds__(256) void binsort_kernel(const int* __restrict__ src,
                                                      const int* __restrict__ dst,
                                                      int E, int CHUNK,
                                                      int* __restrict__ bucket_cursor,
                                                      unsigned int* __restrict__ ebuf,
                                                      int NBUCK) {
    __shared__ int lh[MAXB];     // local counts
    __shared__ int lcur[MAXB];   // local running offset
    __shared__ int gbase[MAXB];  // reserved global base for this block
    int e0 = blockIdx.x * CHUNK;
    int e1 = e0 + CHUNK; if (e1 > E) e1 = E;
    for (int i = threadIdx.x; i < NBUCK; i += 256) { lh[i] = 0; lcur[i] = 0; }
    __syncthreads();
    for (int e = e0 + threadIdx.x; e < e1; e += 256)
        atomicAdd(&lh[dst[e] >> BSHIFT], 1);
    __syncthreads();
    for (int b = threadIdx.x; b < NBUCK; b += 256) {
        int c = lh[b];
        gbase[b] = c ? atomicAdd(&bucket_cursor[b], c) : 0;
    }
    __syncthreads();
    for (int e = e0 + threadIdx.x; e < e1; e += 256) {
        int d = dst[e];
        int s = src[e];
        int b = d >> BSHIFT;
        int off = atomicAdd(&lcur[b], 1);
        ebuf[gbase[b] + off] = (unsigned int)s | ((unsigned int)d << 16);
    }
}

// one block per bucket: derive row_ptr from LDS histogram+scan, then place
// src ids into col within the bucket's exclusive window.
__global__ __launch_bounds__(256) void bucket_fill_kernel(const int* __restrict__ bucket_base,
                                                          const unsigned int* __restrict__ ebuf,
                                                          int* __restrict__ row_ptr,
                                                          int* __restrict__ col, int N) {
    __shared__ int cnt[256];
    __shared__ int scan[256];
    __shared__ int cur[256];
    int b = blockIdx.x;
    int nbase = b << BSHIFT;
    int tid = threadIdx.x;
    int gB = bucket_base[b];
    int gEnd = bucket_base[b + 1];
    cnt[tid] = 0;
    __syncthreads();
    for (int e = gB + tid; e < gEnd; e += 256)
        atomicAdd(&cnt[(ebuf[e] >> 16) - nbase], 1);
    __syncthreads();
    // inclusive Hillis-Steele scan over 256 entries
    int v = cnt[tid];
    scan[tid] = v;
    __syncthreads();
#pragma unroll
    for (int off = 1; off < 256; off <<= 1) {
        int t = (tid >= off) ? scan[tid - off] : 0;
        __syncthreads();
        scan[tid] += t;
        __syncthreads();
    }
    int excl = scan[tid] - v;
    int n = nbase + tid;
    if (n < N) row_ptr[n] = gB + excl;
    cur[tid] = gB + excl;
    __syncthreads();
    for (int e = gB + tid; e < gEnd; e += 256) {
        unsigned int pv = ebuf[e];
        int s = (int)(pv & 0xFFFFu);
        int d = (int)(pv >> 16);
        int p = atomicAdd(&cur[d - nbase], 1);
        col[p] = s;
    }
}

// --------------------------- fp32 -> (hi,lo) -------------------------------

__global__ void convert_x_kernel(const float* __restrict__ x,
                                 unsigned short* __restrict__ xH,
                                 unsigned short* __restrict__ xL, int total4) {
    int i = blockIdx.x * 256 + threadIdx.x;
    if (i >= total4) return;
    float4 v = ((const float4*)x)[i];
    unsigned short h0, h1, h2, h3, l0, l1, l2, l3;
    split2(v.x, h0, l0); split2(v.y, h1, l1); split2(v.z, h2, l2); split2(v.w, h3, l3);
    ((ushort4*)xH)[i] = make_ushort4(h0, h1, h2, h3);
    ((ushort4*)xL)[i] = make_ushort4(l0, l1, l2, l3);
}

__global__ void convert_w_kernel(const float* __restrict__ w0, const float* __restrict__ w1,
                                 const float* __restrict__ w2, const float* __restrict__ w3,
                                 const float* __restrict__ w4, const float* __restrict__ w5,
                                 unsigned short* __restrict__ WH,
                                 unsigned short* __restrict__ WL) {
    int m = blockIdx.y;
    const float* src = (m == 0) ? w0 : (m == 1) ? w1 : (m == 2) ? w2
                       : (m == 3) ? w3 : (m == 4) ? w4 : w5;
    int i = blockIdx.x * 256 + threadIdx.x;
    if (i >= 4096) return;
    float4 v = ((const float4*)src)[i];
    unsigned short h0, h1, h2, h3, l0, l1, l2, l3;
    split2(v.x, h0, l0); split2(v.y, h1, l1); split2(v.z, h2, l2); split2(v.w, h3, l3);
    ((ushort4*)(WH + (size_t)m * 16384))[i] = make_ushort4(h0, h1, h2, h3);
    ((ushort4*)(WL + (size_t)m * 16384))[i] = make_ushort4(l0, l1, l2, l3);
}

// ------------------------------ aggregation --------------------------------

__global__ __launch_bounds__(256) void agg_mean_kernel(
    const unsigned short* __restrict__ inH,
    const int* __restrict__ row_ptr, const int* __restrict__ col,
    unsigned short* __restrict__ mH, unsigned short* __restrict__ mL, int N) {
    int wave = threadIdx.x >> 6;
    int lane = threadIdx.x & 63;
    int n = blockIdx.x * 4 + wave;
    if (n >= N) return;
    int beg = row_ptr[n];
    int end = row_ptr[n + 1];
    float ax = 0.f, ay = 0.f, bx = 0.f, by = 0.f;
    float cx = 0.f, cy = 0.f, dx = 0.f, dy = 0.f;
    int i = beg;
    for (; i + 3 < end; i += 4) {
        int s0 = col[i], s1 = col[i + 1], s2 = col[i + 2], s3 = col[i + 3];
        ushort2 h0 = ((const ushort2*)(inH + (size_t)s0 * 128))[lane];
        ushort2 h1 = ((const ushort2*)(inH + (size_t)s1 * 128))[lane];
        ushort2 h2 = ((const ushort2*)(inH + (size_t)s2 * 128))[lane];
        ushort2 h3 = ((const ushort2*)(inH + (size_t)s3 * 128))[lane];
        ax += bf2f(h0.x); ay += bf2f(h0.y);
        bx += bf2f(h1.x); by += bf2f(h1.y);
        cx += bf2f(h2.x); cy += bf2f(h2.y);
        dx += bf2f(h3.x); dy += bf2f(h3.y);
    }
    for (; i < end; ++i) {
        int s0 = col[i];
        ushort2 h0 = ((const ushort2*)(inH + (size_t)s0 * 128))[lane];
        ax += bf2f(h0.x); ay += bf2f(h0.y);
    }
    int d = end - beg;
    float inv = 1.0f / (float)(d > 0 ? d : 1);
    float vx = (ax + bx + cx + dx) * inv, vy = (ay + by + cy + dy) * inv;
    unsigned short hx, lx, hy, ly;
    split2(vx, hx, lx); split2(vy, hy, ly);
    ((ushort2*)(mH + (size_t)n * 128))[lane] = make_ushort2(hx, hy);
    ((ushort2*)(mL + (size_t)n * 128))[lane] = make_ushort2(lx, ly);
}

// ------------------------- split-bf16 MFMA GEMM ----------------------------

__global__ __launch_bounds__(256, 2) void sage_gemm_mfma(
    const unsigned short* __restrict__ a0H, const unsigned short* __restrict__ a0L,
    const unsigned short* __restrict__ a1H, const unsigned short* __restrict__ a1L,
    const unsigned short* __restrict__ w0H, const unsigned short* __restrict__ w0L,
    const unsigned short* __restrict__ w1H, const unsigned short* __restrict__ w1L,
    const float* __restrict__ bias,
    unsigned short* __restrict__ outH, unsigned short* __restrict__ outL, int N) {
    __shared__ unsigned short Ah[128][40];
    __shared__ unsigned short Al[128][40];
    __shared__ unsigned short Wh[128][40];
    __shared__ unsigned short Wl[128][40];
    int tid = threadIdx.x;
    int n0 = blockIdx.x * 128;
    int wv = tid >> 6, lane = tid & 63;
    int wm = wv & 1, wn = wv >> 1;
    int r16 = lane & 15, q = lane >> 4, q8 = q * 8;

    floatx4 acc[4][4];
#pragma unroll
    for (int mi = 0; mi < 4; ++mi)
#pragma unroll
        for (int ni = 0; ni < 4; ++ni) {
            floatx4 z = {0.f, 0.f, 0.f, 0.f};
            acc[mi][ni] = z;
        }

    int tc = (tid & 3) * 8;
    int tr = tid >> 2;

    for (int part = 0; part < 2; ++part) {
        const unsigned short* AH = part ? a1H : a0H;
        const unsigned short* AL = part ? a1L : a0L;
        const unsigned short* WHp = part ? w1H : w0H;
        const unsigned short* WLp = part ? w1L : w0L;
        for (int kk = 0; kk < 128; kk += 32) {
            __syncthreads();
#pragma unroll
            for (int rr = 0; rr < 2; ++rr) {
                int row = tr + 64 * rr;
                int n = n0 + row;
                ushort8 vh = {0, 0, 0, 0, 0, 0, 0, 0};
                ushort8 vl = {0, 0, 0, 0, 0, 0, 0, 0};
                if (n < N) {
                    vh = *(const ushort8*)&AH[(size_t)n * 128 + kk + tc];
                    vl = *(const ushort8*)&AL[(size_t)n * 128 + kk + tc];
                }
                *(ushort8*)&Ah[row][tc] = vh;
                *(ushort8*)&Al[row][tc] = vl;
                *(ushort8*)&Wh[row][tc] = *(const ushort8*)&WHp[(size_t)row * 128 + kk + tc];
                *(ushort8*)&Wl[row][tc] = *(const ushort8*)&WLp[(size_t)row * 128 + kk + tc];
            }
            __syncthreads();
            short8 ah[4], al[4];
#pragma unroll
            for (int mi = 0; mi < 4; ++mi) {
                int row = 64 * wm + 16 * mi + r16;
                ah[mi] = *(const short8*)&Ah[row][q8];
                al[mi] = *(const short8*)&Al[row][q8];
            }
#pragma unroll
            for (int ni = 0; ni < 4; ++ni) {
                int row = 64 * wn + 16 * ni + r16;
                short8 bh = *(const short8*)&Wh[row][q8];
                short8 bl = *(const short8*)&Wl[row][q8];
#pragma unroll
                for (int mi = 0; mi < 4; ++mi) {
                    acc[mi][ni] = __builtin_amdgcn_mfma_f32_16x16x32_bf16(ah[mi], bh, acc[mi][ni], 0, 0, 0);
                    acc[mi][ni] = __builtin_amdgcn_mfma_f32_16x16x32_bf16(al[mi], bh, acc[mi][ni], 0, 0, 0);
                    acc[mi][ni] = __builtin_amdgcn_mfma_f32_16x16x32_bf16(ah[mi], bl, acc[mi][ni], 0, 0, 0);
                }
            }
        }
    }
#pragma unroll
    for (int ni = 0; ni < 4; ++ni) {
        int j = 64 * wn + 16 * ni + r16;
        float b = bias[j];
#pragma unroll
        for (int mi = 0; mi < 4; ++mi) {
            floatx4 v = acc[mi][ni];
#pragma unroll
            for (int p = 0; p < 4; ++p) {
                int node = n0 + 64 * wm + 16 * mi + 4 * q + p;
                if (node < N) {
                    float val = fmaxf(v[p] + b, 0.f);
                    unsigned short hi, lo;
                    split2(val, hi, lo);
                    outH[(size_t)node * 128 + j] = hi;
                    outL[(size_t)node * 128 + j] = lo;
                }
            }
        }
    }
}

// ------------------------------ fused head ---------------------------------

__global__ __launch_bounds__(256) void head_fused_kernel(
    const unsigned short* __restrict__ hH, const unsigned short* __restrict__ hL,
    const float* __restrict__ Wh1, const float* __restrict__ bh1,
    const float* __restrict__ Wh2, const float* __restrict__ bh2,
    float* __restrict__ out, int N) {
    __shared__ float As[64][33];
    __shared__ float Bs[32][65];
    __shared__ float Hs[64][65];
    int tid = threadIdx.x;
    int n0 = blockIdx.x * 64;
    int ti = tid & 15;
    int tj = tid >> 4;

    float acc[4][4];
#pragma unroll
    for (int r = 0; r < 4; ++r)
#pragma unroll
        for (int c = 0; c < 4; ++c) acc[r][c] = 0.f;

    for (int kk = 0; kk < 128; kk += 32) {
        int ks = tid & 31, i0 = tid >> 5;
#pragma unroll
        for (int r = 0; r < 8; ++r) {
            int i = i0 + 8 * r;
            int n = n0 + i;
            As[i][ks] = (n < N)
                ? (bf2f(hH[(size_t)n * 128 + kk + ks]) + bf2f(hL[(size_t)n * 128 + kk + ks]))
                : 0.f;
        }
        int jj0 = tid >> 5;
#pragma unroll
        for (int r = 0; r < 8; ++r) {
            int j = jj0 + 8 * r;
            Bs[ks][j] = Wh1[(size_t)j * 128 + kk + ks];
        }
        __syncthreads();
#pragma unroll 4
        for (int k = 0; k < 32; ++k) {
            float4 b = *(const float4*)&Bs[k][4 * tj];
#pragma unroll
            for (int r = 0; r < 4; ++r) {
                float a = As[4 * ti + r][k];
                acc[r][0] += a * b.x; acc[r][1] += a * b.y;
                acc[r][2] += a * b.z; acc[r][3] += a * b.w;
            }
        }
        __syncthreads();
    }
    float4 bv = *(const float4*)&bh1[4 * tj];
#pragma unroll
    for (int r = 0; r < 4; ++r) {
        int i = 4 * ti + r;
        Hs[i][4 * tj + 0] = fmaxf(acc[r][0] + bv.x, 0.f);
        Hs[i][4 * tj + 1] = fmaxf(acc[r][1] + bv.y, 0.f);
        Hs[i][4 * tj + 2] = fmaxf(acc[r][2] + bv.z, 0.f);
        Hs[i][4 * tj + 3] = fmaxf(acc[r][3] + bv.w, 0.f);
    }
    __syncthreads();
    int ni = tid >> 2;
    int c = tid & 3;
    const float* w = Wh2 + (size_t)c * 64;
    float s = bh2[c];
#pragma unroll 8
    for (int k = 0; k < 64; ++k) s += Hs[ni][k] * w[k];
    int n = n0 + ni;
    if (n < N) out[(size_t)n * 4 + c] = s;
}

// ------------------------------- launcher ----------------------------------

extern "C" void kernel_launch(void* const* d_in, const int* in_sizes, int n_in,
                              void* d_out, int out_size, void* d_ws, size_t ws_size,
                              hipStream_t stream) {
    const float* x   = (const float*)d_in[0];
    const int*   ei  = (const int*)d_in[1];
    const float* Wl0 = (const float*)d_in[2];
    const float* bl0 = (const float*)d_in[3];
    const float* Wr0 = (const float*)d_in[4];
    const float* Wl1 = (const float*)d_in[5];
    const float* bl1 = (const float*)d_in[6];
    const float* Wr1 = (const float*)d_in[7];
    const float* Wl2 = (const float*)d_in[8];
    const float* bl2 = (const float*)d_in[9];
    const float* Wr2 = (const float*)d_in[10];
    const float* Wh1 = (const float*)d_in[11];
    const float* bh1 = (const float*)d_in[12];
    const float* Wh2 = (const float*)d_in[13];
    const float* bh2 = (const float*)d_in[14];
    float* out = (float*)d_out;

    const int N = in_sizes[0] / 128;
    const int E = in_sizes[1] / 2;
    const int* src = ei;
    const int* dst = ei + E;
    const int NBUCK = (N + 255) >> BSHIFT;

    int* row_ptr       = (int*)d_ws;                 // N+1
    int* bh            = row_ptr + N + 1;            // NBUCK
    int* bucket_base   = bh + NBUCK;                 // NBUCK+1
    int* bucket_cursor = bucket_base + NBUCK + 1;    // NBUCK
    unsigned int* ebuf = (unsigned int*)(bucket_cursor + NBUCK);  // E
    int* col           = (int*)(ebuf + E);           // E
    size_t ioff = (((size_t)(N + 1 + 3 * NBUCK + 1 + 2 * (size_t)E)) * sizeof(int) + 255) & ~(size_t)255;
    unsigned short* u0H = (unsigned short*)((char*)d_ws + ioff);
    unsigned short* u0L = u0H + (size_t)N * 128;
    unsigned short* mH  = u0L + (size_t)N * 128;
    unsigned short* mL  = mH + (size_t)N * 128;
    unsigned short* aH  = mL + (size_t)N * 128;
    unsigned short* aL  = aH + (size_t)N * 128;
    unsigned short* WH  = aL + (size_t)N * 128;      // 6 x 16384
    unsigned short* WL  = WH + 6 * 16384;

    const int nb4 = (N + 3) / 4;
    const int gb64 = (N + 63) / 64;
    const int gb128 = (N + 127) / 128;
    const int CHUNK = 16384;
    const int nchunk = (E + CHUNK - 1) / CHUNK;

    // CSR build (counting sort)
    hipMemsetAsync(bh, 0, (size_t)NBUCK * sizeof(int), stream);
    hist_kernel<<<128, 256, 0, stream>>>(dst, E, bh, NBUCK);
    bucket_scan_kernel<<<1, 256, 0, stream>>>(bh, bucket_base, bucket_cursor, row_ptr, NBUCK, N, E);
    binsort_kernel<<<nchunk, 256, 0, stream>>>(src, dst, E, CHUNK, bucket_cursor, ebuf, NBUCK);
    bucket_fill_kernel<<<NBUCK, 256, 0, stream>>>(bucket_base, ebuf, row_ptr, col, N);

    // convert inputs to (hi,lo) pairs
    convert_x_kernel<<<(N * 32 + 255) / 256, 256, 0, stream>>>(x, u0H, u0L, N * 32);
    dim3 wgrid(16, 6);
    convert_w_kernel<<<wgrid, 256, 0, stream>>>(Wl0, Wr0, Wl1, Wr1, Wl2, Wr2, WH, WL);

    // layer 0: A0=mean(x), A1=x
    agg_mean_kernel<<<nb4, 256, 0, stream>>>(u0H, row_ptr, col, mH, mL, N);
    sage_gemm_mfma<<<gb128, 256, 0, stream>>>(mH, mL, u0H, u0L,
                                              WH + 0 * 16384, WL + 0 * 16384,
                                              WH + 1 * 16384, WL + 1 * 16384,
                                              bl0, aH, aL, N);
    // layer 1
    agg_mean_kernel<<<nb4, 256, 0, stream>>>(aH, row_ptr, col, mH, mL, N);
    sage_gemm_mfma<<<gb128, 256, 0, stream>>>(mH, mL, aH, aL,
                                              WH + 2 * 16384, WL + 2 * 16384,
                                              WH + 3 * 16384, WL + 3 * 16384,
                                              bl1, u0H, u0L, N);
    // layer 2
    agg_mean_kernel<<<nb4, 256, 0, stream>>>(u0H, row_ptr, col, mH, mL, N);
    sage_gemm_mfma<<<gb128, 256, 0, stream>>>(mH, mL, u0H, u0L,
                                              WH + 4 * 16384, WL + 4 * 16384,
                                              WH + 5 * 16384, WL + 5 * 16384,
                                              bl2, aH, aL, N);

    // fused head MLP
    head_fused_kernel<<<gb64, 256, 0, stream>>>(aH, aL, Wh1, bh1, Wh2, bh2, out, N);
}

// Round 8
// 392.287 us; speedup vs baseline: 1.0844x; 1.0191x over previous
//
#include <hip/hip_runtime.h>
#include <cstdint>
#include <cstddef>

// ---------------------------------------------------------------------------
// StationGNN: 3x GraphSAGE(mean) + MLP head.
// R1: fused head. R2: parallel scan. R3: split-bf16 MFMA GEMMs.
// R4: hi-only bf16 gather. R5: bucketed fill (FAILED: shared frontier lines).
// R6: counting-sort binning, CU-exclusive runs (writes 40->3.4MB) but grid
//     was 49 blocks -> 1.9% occupancy, still 46us.
// R7: CHUNK 16384->2048 (391 blocks) and buckets 256->128 nodes (391 fill
//     blocks): same write locality, 8x the parallelism.
// ---------------------------------------------------------------------------

typedef __attribute__((ext_vector_type(8))) short short8;
typedef __attribute__((ext_vector_type(8))) unsigned short ushort8;
typedef __attribute__((ext_vector_type(4))) float floatx4;

#define BSHIFT 7                 // 128 nodes per bucket
#define MAXB 512                 // supports N <= 65536 at BSHIFT=7

__device__ __forceinline__ float bf2f(unsigned short h) {
    return __uint_as_float(((unsigned int)h) << 16);
}
__device__ __forceinline__ void split2(float x, unsigned short& hi, unsigned short& lo) {
    unsigned int u = __float_as_uint(x);
    hi = (unsigned short)(u >> 16);
    float r = x - __uint_as_float(u & 0xFFFF0000u);
    lo = (unsigned short)(__float_as_uint(r) >> 16);
}

// ------------------------------ CSR build ----------------------------------

__global__ __launch_bounds__(256) void hist_kernel(const int* __restrict__ dst, int E,
                                                   int* __restrict__ bh, int NBUCK) {
    __shared__ int lh[MAXB];
    for (int i = threadIdx.x; i < NBUCK; i += 256) lh[i] = 0;
    __syncthreads();
    for (int e = blockIdx.x * 256 + threadIdx.x; e < E; e += gridDim.x * 256)
        atomicAdd(&lh[dst[e] >> BSHIFT], 1);
    __syncthreads();
    for (int i = threadIdx.x; i < NBUCK; i += 256)
        if (lh[i]) atomicAdd(&bh[i], lh[i]);
}

__global__ __launch_bounds__(256) void bucket_scan_kernel(const int* __restrict__ bh,
                                                          int* __restrict__ bucket_base,
                                                          int* __restrict__ bucket_cursor,
                                                          int* __restrict__ row_ptr,
                                                          int NBUCK, int N, int E) {
    if (threadIdx.x == 0) {
        int run = 0;
        for (int i = 0; i < NBUCK; ++i) {
            bucket_base[i] = run;
            bucket_cursor[i] = run;
            run += bh[i];
        }
        bucket_base[NBUCK] = run;
        row_ptr[N] = E;
    }
}

// binsort: each block owns a contiguous edge chunk; reserves private runs
// per bucket; scatters packed (s|d<<16) into its exclusive runs.
__global__ __launch_bounds__(256) void binsort_kernel(const int* __restrict__ src,
                                                      const int* __restrict__ dst,
                                                      int E, int CHUNK,
                                                      int* __restrict__ bucket_cursor,
                                                      unsigned int* __restrict__ ebuf,
                                                      int NBUCK) {
    __shared__ int lh[MAXB];
    __shared__ int lcur[MAXB];
    __shared__ int gbase[MAXB];
    int e0 = blockIdx.x * CHUNK;
    int e1 = e0 + CHUNK; if (e1 > E) e1 = E;
    for (int i = threadIdx.x; i < NBUCK; i += 256) { lh[i] = 0; lcur[i] = 0; }
    __syncthreads();
    for (int e = e0 + threadIdx.x; e < e1; e += 256)
        atomicAdd(&lh[dst[e] >> BSHIFT], 1);
    __syncthreads();
    for (int b = threadIdx.x; b < NBUCK; b += 256) {
        int c = lh[b];
        gbase[b] = c ? atomicAdd(&bucket_cursor[b], c) : 0;
    }
    __syncthreads();
    for (int e = e0 + threadIdx.x; e < e1; e += 256) {
        int d = dst[e];
        int s = src[e];
        int b = d >> BSHIFT;
        int off = atomicAdd(&lcur[b], 1);
        ebuf[gbase[b] + off] = (unsigned int)s | ((unsigned int)d << 16);
    }
}

// one block per bucket (128 nodes): derive row_ptr from LDS histogram+scan,
// then place src ids into col within the bucket's exclusive window.
__global__ __launch_bounds__(256) void bucket_fill_kernel(const int* __restrict__ bucket_base,
                                                          const unsigned int* __restrict__ ebuf,
                                                          int* __restrict__ row_ptr,
                                                          int* __restrict__ col, int N) {
    __shared__ int cnt[256];
    __shared__ int scan[256];
    __shared__ int cur[256];
    int b = blockIdx.x;
    int nbase = b << BSHIFT;
    int tid = threadIdx.x;
    int gB = bucket_base[b];
    int gEnd = bucket_base[b + 1];
    cnt[tid] = 0;
    __syncthreads();
    for (int e = gB + tid; e < gEnd; e += 256)
        atomicAdd(&cnt[(ebuf[e] >> 16) - nbase], 1);
    __syncthreads();
    int v = cnt[tid];
    scan[tid] = v;
    __syncthreads();
#pragma unroll
    for (int off = 1; off < 256; off <<= 1) {
        int t = (tid >= off) ? scan[tid - off] : 0;
        __syncthreads();
        scan[tid] += t;
        __syncthreads();
    }
    int excl = scan[tid] - v;
    int n = nbase + tid;
    if (tid < 128 && n < N) row_ptr[n] = gB + excl;
    cur[tid] = gB + excl;
    __syncthreads();
    for (int e = gB + tid; e < gEnd; e += 256) {
        unsigned int pv = ebuf[e];
        int s = (int)(pv & 0xFFFFu);
        int d = (int)(pv >> 16);
        int p = atomicAdd(&cur[d - nbase], 1);
        col[p] = s;
    }
}

// --------------------------- fp32 -> (hi,lo) -------------------------------

__global__ void convert_x_kernel(const float* __restrict__ x,
                                 unsigned short* __restrict__ xH,
                                 unsigned short* __restrict__ xL, int total4) {
    int i = blockIdx.x * 256 + threadIdx.x;
    if (i >= total4) return;
    float4 v = ((const float4*)x)[i];
    unsigned short h0, h1, h2, h3, l0, l1, l2, l3;
    split2(v.x, h0, l0); split2(v.y, h1, l1); split2(v.z, h2, l2); split2(v.w, h3, l3);
    ((ushort4*)xH)[i] = make_ushort4(h0, h1, h2, h3);
    ((ushort4*)xL)[i] = make_ushort4(l0, l1, l2, l3);
}

__global__ void convert_w_kernel(const float* __restrict__ w0, const float* __restrict__ w1,
                                 const float* __restrict__ w2, const float* __restrict__ w3,
                                 const float* __restrict__ w4, const float* __restrict__ w5,
                                 unsigned short* __restrict__ WH,
                                 unsigned short* __restrict__ WL) {
    int m = blockIdx.y;
    const float* src = (m == 0) ? w0 : (m == 1) ? w1 : (m == 2) ? w2
                       : (m == 3) ? w3 : (m == 4) ? w4 : w5;
    int i = blockIdx.x * 256 + threadIdx.x;
    if (i >= 4096) return;
    float4 v = ((const float4*)src)[i];
    unsigned short h0, h1, h2, h3, l0, l1, l2, l3;
    split2(v.x, h0, l0); split2(v.y, h1, l1); split2(v.z, h2, l2); split2(v.w, h3, l3);
    ((ushort4*)(WH + (size_t)m * 16384))[i] = make_ushort4(h0, h1, h2, h3);
    ((ushort4*)(WL + (size_t)m * 16384))[i] = make_ushort4(l0, l1, l2, l3);
}

// ------------------------------ aggregation --------------------------------

__global__ __launch_bounds__(256) void agg_mean_kernel(
    const unsigned short* __restrict__ inH,
    const int* __restrict__ row_ptr, const int* __restrict__ col,
    unsigned short* __restrict__ mH, unsigned short* __restrict__ mL, int N) {
    int wave = threadIdx.x >> 6;
    int lane = threadIdx.x & 63;
    int n = blockIdx.x * 4 + wave;
    if (n >= N) return;
    int beg = row_ptr[n];
    int end = row_ptr[n + 1];
    float ax = 0.f, ay = 0.f, bx = 0.f, by = 0.f;
    float cx = 0.f, cy = 0.f, dx = 0.f, dy = 0.f;
    int i = beg;
    for (; i + 3 < end; i += 4) {
        int s0 = col[i], s1 = col[i + 1], s2 = col[i + 2], s3 = col[i + 3];
        ushort2 h0 = ((const ushort2*)(inH + (size_t)s0 * 128))[lane];
        ushort2 h1 = ((const ushort2*)(inH + (size_t)s1 * 128))[lane];
        ushort2 h2 = ((const ushort2*)(inH + (size_t)s2 * 128))[lane];
        ushort2 h3 = ((const ushort2*)(inH + (size_t)s3 * 128))[lane];
        ax += bf2f(h0.x); ay += bf2f(h0.y);
        bx += bf2f(h1.x); by += bf2f(h1.y);
        cx += bf2f(h2.x); cy += bf2f(h2.y);
        dx += bf2f(h3.x); dy += bf2f(h3.y);
    }
    for (; i < end; ++i) {
        int s0 = col[i];
        ushort2 h0 = ((const ushort2*)(inH + (size_t)s0 * 128))[lane];
        ax += bf2f(h0.x); ay += bf2f(h0.y);
    }
    int d = end - beg;
    float inv = 1.0f / (float)(d > 0 ? d : 1);
    float vx = (ax + bx + cx + dx) * inv, vy = (ay + by + cy + dy) * inv;
    unsigned short hx, lx, hy, ly;
    split2(vx, hx, lx); split2(vy, hy, ly);
    ((ushort2*)(mH + (size_t)n * 128))[lane] = make_ushort2(hx, hy);
    ((ushort2*)(mL + (size_t)n * 128))[lane] = make_ushort2(lx, ly);
}

// ------------------------- split-bf16 MFMA GEMM ----------------------------

__global__ __launch_bounds__(256, 2) void sage_gemm_mfma(
    const unsigned short* __restrict__ a0H, const unsigned short* __restrict__ a0L,
    const unsigned short* __restrict__ a1H, const unsigned short* __restrict__ a1L,
    const unsigned short* __restrict__ w0H, const unsigned short* __restrict__ w0L,
    const unsigned short* __restrict__ w1H, const unsigned short* __restrict__ w1L,
    const float* __restrict__ bias,
    unsigned short* __restrict__ outH, unsigned short* __restrict__ outL, int N) {
    __shared__ unsigned short Ah[128][40];
    __shared__ unsigned short Al[128][40];
    __shared__ unsigned short Wh[128][40];
    __shared__ unsigned short Wl[128][40];
    int tid = threadIdx.x;
    int n0 = blockIdx.x * 128;
    int wv = tid >> 6, lane = tid & 63;
    int wm = wv & 1, wn = wv >> 1;
    int r16 = lane & 15, q = lane >> 4, q8 = q * 8;

    floatx4 acc[4][4];
#pragma unroll
    for (int mi = 0; mi < 4; ++mi)
#pragma unroll
        for (int ni = 0; ni < 4; ++ni) {
            floatx4 z = {0.f, 0.f, 0.f, 0.f};
            acc[mi][ni] = z;
        }

    int tc = (tid & 3) * 8;
    int tr = tid >> 2;

    for (int part = 0; part < 2; ++part) {
        const unsigned short* AH = part ? a1H : a0H;
        const unsigned short* AL = part ? a1L : a0L;
        const unsigned short* WHp = part ? w1H : w0H;
        const unsigned short* WLp = part ? w1L : w0L;
        for (int kk = 0; kk < 128; kk += 32) {
            __syncthreads();
#pragma unroll
            for (int rr = 0; rr < 2; ++rr) {
                int row = tr + 64 * rr;
                int n = n0 + row;
                ushort8 vh = {0, 0, 0, 0, 0, 0, 0, 0};
                ushort8 vl = {0, 0, 0, 0, 0, 0, 0, 0};
                if (n < N) {
                    vh = *(const ushort8*)&AH[(size_t)n * 128 + kk + tc];
                    vl = *(const ushort8*)&AL[(size_t)n * 128 + kk + tc];
                }
                *(ushort8*)&Ah[row][tc] = vh;
                *(ushort8*)&Al[row][tc] = vl;
                *(ushort8*)&Wh[row][tc] = *(const ushort8*)&WHp[(size_t)row * 128 + kk + tc];
                *(ushort8*)&Wl[row][tc] = *(const ushort8*)&WLp[(size_t)row * 128 + kk + tc];
            }
            __syncthreads();
            short8 ah[4], al[4];
#pragma unroll
            for (int mi = 0; mi < 4; ++mi) {
                int row = 64 * wm + 16 * mi + r16;
                ah[mi] = *(const short8*)&Ah[row][q8];
                al[mi] = *(const short8*)&Al[row][q8];
            }
#pragma unroll
            for (int ni = 0; ni < 4; ++ni) {
                int row = 64 * wn + 16 * ni + r16;
                short8 bh = *(const short8*)&Wh[row][q8];
                short8 bl = *(const short8*)&Wl[row][q8];
#pragma unroll
                for (int mi = 0; mi < 4; ++mi) {
                    acc[mi][ni] = __builtin_amdgcn_mfma_f32_16x16x32_bf16(ah[mi], bh, acc[mi][ni], 0, 0, 0);
                    acc[mi][ni] = __builtin_amdgcn_mfma_f32_16x16x32_bf16(al[mi], bh, acc[mi][ni], 0, 0, 0);
                    acc[mi][ni] = __builtin_amdgcn_mfma_f32_16x16x32_bf16(ah[mi], bl, acc[mi][ni], 0, 0, 0);
                }
            }
        }
    }
#pragma unroll
    for (int ni = 0; ni < 4; ++ni) {
        int j = 64 * wn + 16 * ni + r16;
        float b = bias[j];
#pragma unroll
        for (int mi = 0; mi < 4; ++mi) {
            floatx4 v = acc[mi][ni];
#pragma unroll
            for (int p = 0; p < 4; ++p) {
                int node = n0 + 64 * wm + 16 * mi + 4 * q + p;
                if (node < N) {
                    float val = fmaxf(v[p] + b, 0.f);
                    unsigned short hi, lo;
                    split2(val, hi, lo);
                    outH[(size_t)node * 128 + j] = hi;
                    outL[(size_t)node * 128 + j] = lo;
                }
            }
        }
    }
}

// ------------------------------ fused head ---------------------------------

__global__ __launch_bounds__(256) void head_fused_kernel(
    const unsigned short* __restrict__ hH, const unsigned short* __restrict__ hL,
    const float* __restrict__ Wh1, const float* __restrict__ bh1,
    const float* __restrict__ Wh2, const float* __restrict__ bh2,
    float* __restrict__ out, int N) {
    __shared__ float As[64][33];
    __shared__ float Bs[32][65];
    __shared__ float Hs[64][65];
    int tid = threadIdx.x;
    int n0 = blockIdx.x * 64;
    int ti = tid & 15;
    int tj = tid >> 4;

    float acc[4][4];
#pragma unroll
    for (int r = 0; r < 4; ++r)
#pragma unroll
        for (int c = 0; c < 4; ++c) acc[r][c] = 0.f;

    for (int kk = 0; kk < 128; kk += 32) {
        int ks = tid & 31, i0 = tid >> 5;
#pragma unroll
        for (int r = 0; r < 8; ++r) {
            int i = i0 + 8 * r;
            int n = n0 + i;
            As[i][ks] = (n < N)
                ? (bf2f(hH[(size_t)n * 128 + kk + ks]) + bf2f(hL[(size_t)n * 128 + kk + ks]))
                : 0.f;
        }
        int jj0 = tid >> 5;
#pragma unroll
        for (int r = 0; r < 8; ++r) {
            int j = jj0 + 8 * r;
            Bs[ks][j] = Wh1[(size_t)j * 128 + kk + ks];
        }
        __syncthreads();
#pragma unroll 4
        for (int k = 0; k < 32; ++k) {
            float4 b = *(const float4*)&Bs[k][4 * tj];
#pragma unroll
            for (int r = 0; r < 4; ++r) {
                float a = As[4 * ti + r][k];
                acc[r][0] += a * b.x; acc[r][1] += a * b.y;
                acc[r][2] += a * b.z; acc[r][3] += a * b.w;
            }
        }
        __syncthreads();
    }
    float4 bv = *(const float4*)&bh1[4 * tj];
#pragma unroll
    for (int r = 0; r < 4; ++r) {
        int i = 4 * ti + r;
        Hs[i][4 * tj + 0] = fmaxf(acc[r][0] + bv.x, 0.f);
        Hs[i][4 * tj + 1] = fmaxf(acc[r][1] + bv.y, 0.f);
        Hs[i][4 * tj + 2] = fmaxf(acc[r][2] + bv.z, 0.f);
        Hs[i][4 * tj + 3] = fmaxf(acc[r][3] + bv.w, 0.f);
    }
    __syncthreads();
    int ni = tid >> 2;
    int c = tid & 3;
    const float* w = Wh2 + (size_t)c * 64;
    float s = bh2[c];
#pragma unroll 8
    for (int k = 0; k < 64; ++k) s += Hs[ni][k] * w[k];
    int n = n0 + ni;
    if (n < N) out[(size_t)n * 4 + c] = s;
}

// ------------------------------- launcher ----------------------------------

extern "C" void kernel_launch(void* const* d_in, const int* in_sizes, int n_in,
                              void* d_out, int out_size, void* d_ws, size_t ws_size,
                              hipStream_t stream) {
    const float* x   = (const float*)d_in[0];
    const int*   ei  = (const int*)d_in[1];
    const float* Wl0 = (const float*)d_in[2];
    const float* bl0 = (const float*)d_in[3];
    const float* Wr0 = (const float*)d_in[4];
    const float* Wl1 = (const float*)d_in[5];
    const float* bl1 = (const float*)d_in[6];
    const float* Wr1 = (const float*)d_in[7];
    const float* Wl2 = (const float*)d_in[8];
    const float* bl2 = (const float*)d_in[9];
    const float* Wr2 = (const float*)d_in[10];
    const float* Wh1 = (const float*)d_in[11];
    const float* bh1 = (const float*)d_in[12];
    const float* Wh2 = (const float*)d_in[13];
    const float* bh2 = (const float*)d_in[14];
    float* out = (float*)d_out;

    const int N = in_sizes[0] / 128;
    const int E = in_sizes[1] / 2;
    const int* src = ei;
    const int* dst = ei + E;
    const int NBUCK = ((N + 127) >> BSHIFT);

    int* row_ptr       = (int*)d_ws;                 // N+1
    int* bh            = row_ptr + N + 1;            // NBUCK
    int* bucket_base   = bh + NBUCK;                 // NBUCK+1
    int* bucket_cursor = bucket_base + NBUCK + 1;    // NBUCK
    unsigned int* ebuf = (unsigned int*)(bucket_cursor + NBUCK);  // E
    int* col           = (int*)(ebuf + E);           // E
    size_t ioff = (((size_t)(N + 1 + 3 * NBUCK + 1 + 2 * (size_t)E)) * sizeof(int) + 255) & ~(size_t)255;
    unsigned short* u0H = (unsigned short*)((char*)d_ws + ioff);
    unsigned short* u0L = u0H + (size_t)N * 128;
    unsigned short* mH  = u0L + (size_t)N * 128;
    unsigned short* mL  = mH + (size_t)N * 128;
    unsigned short* aH  = mL + (size_t)N * 128;
    unsigned short* aL  = aH + (size_t)N * 128;
    unsigned short* WH  = aL + (size_t)N * 128;      // 6 x 16384
    unsigned short* WL  = WH + 6 * 16384;

    const int nb4 = (N + 3) / 4;
    const int gb64 = (N + 63) / 64;
    const int gb128 = (N + 127) / 128;
    const int CHUNK = 2048;
    const int nchunk = (E + CHUNK - 1) / CHUNK;

    // CSR build (counting sort)
    hipMemsetAsync(bh, 0, (size_t)NBUCK * sizeof(int), stream);
    hist_kernel<<<256, 256, 0, stream>>>(dst, E, bh, NBUCK);
    bucket_scan_kernel<<<1, 256, 0, stream>>>(bh, bucket_base, bucket_cursor, row_ptr, NBUCK, N, E);
    binsort_kernel<<<nchunk, 256, 0, stream>>>(src, dst, E, CHUNK, bucket_cursor, ebuf, NBUCK);
    bucket_fill_kernel<<<NBUCK, 256, 0, stream>>>(bucket_base, ebuf, row_ptr, col, N);

    // convert inputs to (hi,lo) pairs
    convert_x_kernel<<<(N * 32 + 255) / 256, 256, 0, stream>>>(x, u0H, u0L, N * 32);
    dim3 wgrid(16, 6);
    convert_w_kernel<<<wgrid, 256, 0, stream>>>(Wl0, Wr0, Wl1, Wr1, Wl2, Wr2, WH, WL);

    // layer 0: A0=mean(x), A1=x
    agg_mean_kernel<<<nb4, 256, 0, stream>>>(u0H, row_ptr, col, mH, mL, N);
    sage_gemm_mfma<<<gb128, 256, 0, stream>>>(mH, mL, u0H, u0L,
                                              WH + 0 * 16384, WL + 0 * 16384,
                                              WH + 1 * 16384, WL + 1 * 16384,
                                              bl0, aH, aL, N);
    // layer 1
    agg_mean_kernel<<<nb4, 256, 0, stream>>>(aH, row_ptr, col, mH, mL, N);
    sage_gemm_mfma<<<gb128, 256, 0, stream>>>(mH, mL, aH, aL,
                                              WH + 2 * 16384, WL + 2 * 16384,
                                              WH + 3 * 16384, WL + 3 * 16384,
                                              bl1, u0H, u0L, N);
    // layer 2
    agg_mean_kernel<<<nb4, 256, 0, stream>>>(u0H, row_ptr, col, mH, mL, N);
    sage_gemm_mfma<<<gb128, 256, 0, stream>>>(mH, mL, u0H, u0L,
                                              WH + 4 * 16384, WL + 4 * 16384,
                                              WH + 5 * 16384, WL + 5 * 16384,
                                              bl2, aH, aL, N);

    // fused head MLP
    head_fused_kernel<<<gb64, 256, 0, stream>>>(aH, aL, Wh1, bh1, Wh2, bh2, out, N);
}